// Round 21
// baseline (90.631 us; speedup 1.0000x reference)
//
#include <hip/hip_runtime.h>
#include <hip/hip_bf16.h>
#include <stdint.h>

// CA model: B=8, H=256, W=256, C=16, HID=128, steps=2 (fixed by setup_inputs).
// Round 21: TEMPORAL FUSION via overlapped tiling — both CA steps in one
// kernel, no grid sync. Output tile 14x14; step-1 computed on the 16x16 mid
// region (one MTSTEP/row) from an 18x18 x-stage; step-2 reads mid from LDS.
// tmp tensor eliminated (-33MB write, -33MB read, -1 dispatch, -1 restage,
// weights loaded once). mid zeroed outside image (zero-pad for step-2 conv);
// stores predicated to the 14x14 valid window; discarded lanes' garbage
// stays in their own matmul columns. Row math identical to round 19.

#define NB 8
#define NH 256
#define NW 256
#define NC 16
#define TO 14            // output tile side
#define NT 19            // ceil(256/14)

typedef __attribute__((ext_vector_type(8))) short short8;
typedef __attribute__((ext_vector_type(4))) float floatx4;

__host__ __device__ inline void tf2x32(uint32_t k0, uint32_t k1,
                                       uint32_t x0, uint32_t x1,
                                       uint32_t& o0, uint32_t& o1) {
  const uint32_t ks2 = k0 ^ k1 ^ 0x1BD11BDAu;
  x0 += k0; x1 += k1;
#define RL(v, d) (((v) << (d)) | ((v) >> (32 - (d))))
#define R4(a, b, c, d)                          \
  x0 += x1; x1 = RL(x1, a); x1 ^= x0;           \
  x0 += x1; x1 = RL(x1, b); x1 ^= x0;           \
  x0 += x1; x1 = RL(x1, c); x1 ^= x0;           \
  x0 += x1; x1 = RL(x1, d); x1 ^= x0;
  R4(13, 15, 26, 6);  x0 += k1;  x1 += ks2 + 1u;
  R4(17, 29, 16, 24); x0 += ks2; x1 += k0 + 2u;
  R4(13, 15, 26, 6);  x0 += k0;  x1 += k1 + 3u;
  R4(17, 29, 16, 24); x0 += k1;  x1 += ks2 + 4u;
  R4(13, 15, 26, 6);  x0 += ks2; x1 += k0 + 5u;
#undef R4
#undef RL
  o0 = x0; o1 = x1;
}

__device__ inline short bfr(float x) {
  __hip_bfloat16 h = __float2bfloat16(x);
  return *reinterpret_cast<short*>(&h);
}

// ---- parallel prep: 20 blocks x 64 lanes, one fragment per block ----
// W0 sobel columns pre-scaled by 1/8 (power-of-2, bit-identical products) so
// kernel tap weights are inline consts; K-pad bias at k=48 (A=b0[o], B=1).
__global__ __launch_bounds__(64) void ca_prep(
    const float* __restrict__ W0, const float* __restrict__ b0,
    const float* __restrict__ W1, short* __restrict__ wbuf) {
  const int lane = threadIdx.x;
  const int c15 = lane & 15;
  const int g = lane >> 4;
  const int fi = blockIdx.x;   // 0..19
  short8 f;
  if (fi < 16) {
    const int n = fi >> 1;
    const int o = 16 * n + c15;
    if ((fi & 1) == 0) {
      const float s0 = (g < 2) ? 1.0f : 0.125f;   // identity | c1(scaled)
      const float* p = W0 + o * 48 + 8 * g;
      const floatx4 v0 = *reinterpret_cast<const floatx4*>(p);
      const floatx4 v1 = *reinterpret_cast<const floatx4*>(p + 4);
      f[0] = bfr(v0.x * s0); f[1] = bfr(v0.y * s0);
      f[2] = bfr(v0.z * s0); f[3] = bfr(v0.w * s0);
      f[4] = bfr(v1.x * s0); f[5] = bfr(v1.y * s0);
      f[6] = bfr(v1.z * s0); f[7] = bfr(v1.w * s0);
    } else {
      if (g < 2) {   // c2 columns (scaled)
        const float* p1 = W0 + o * 48 + 32 + 8 * g;
        const floatx4 u0 = *reinterpret_cast<const floatx4*>(p1);
        const floatx4 u1 = *reinterpret_cast<const floatx4*>(p1 + 4);
        f[0] = bfr(u0.x * 0.125f); f[1] = bfr(u0.y * 0.125f);
        f[2] = bfr(u0.z * 0.125f); f[3] = bfr(u0.w * 0.125f);
        f[4] = bfr(u1.x * 0.125f); f[5] = bfr(u1.y * 0.125f);
        f[6] = bfr(u1.z * 0.125f); f[7] = bfr(u1.w * 0.125f);
      } else {
#pragma unroll
        for (int j = 0; j < 8; ++j) f[j] = 0;
        if (g == 2) f[0] = bfr(b0[o]);   // A[o][48] = b0[o] (K-pad bias)
      }
    }
  } else {
    const int s = fi - 16;   // tau(s,8g+j)=32s+16*(j>>2)+4g+(j&3)
    const float* p = W1 + c15 * 128;
#pragma unroll
    for (int j = 0; j < 8; ++j)
      f[j] = bfr(p[32 * s + 16 * (j >> 2) + 4 * g + (j & 3)]);
  }
  reinterpret_cast<short8*>(wbuf)[fi * 64 + lane] = f;
}

template <bool PRE>
__global__ __launch_bounds__(64, 2) void ca_fused(
    const float* __restrict__ xin, float* __restrict__ xout,
    const float* __restrict__ W0, const float* __restrict__ b0,
    const float* __restrict__ W1, const short* __restrict__ wfrag,
    uint32_t fa0, uint32_t fa1, uint32_t fb0, uint32_t fb1) {
  // x stage: 18x18x16 fp32; mid (step-1 result): 16 rows x 18 cols (2 pad)
  __shared__ float xst[18 * 18 * 16];
  __shared__ float mid[16 * 18 * 16];

  const int tid = threadIdx.x;
  const int bt = blockIdx.x;
  const int tw = bt % NT;
  const int t2 = bt / NT;
  const int th = t2 % NT;
  const int b = t2 / NT;
  const int h0 = TO * th;
  const int w0 = TO * tw;

  const int lane = tid;
  const int c15 = lane & 15;
  const int g = lane >> 4;

  auto addr = [&](float* base, int row, int col, int chunk) -> floatx4* {
    const int off = (row * 18 + col) * 64 + ((chunk ^ ((col >> 1) & 3)) << 4);
    return reinterpret_cast<floatx4*>(reinterpret_cast<char*>(base) + off);
  };

  // ---- weight fragments, loaded once ----
  short8 w0f[8][2];
  short8 w1f[4];
  if constexpr (PRE) {
    const short8* wf = reinterpret_cast<const short8*>(wfrag);
#pragma unroll
    for (int n = 0; n < 8; ++n) {
      w0f[n][0] = wf[(2 * n) * 64 + lane];
      w0f[n][1] = wf[(2 * n + 1) * 64 + lane];
    }
#pragma unroll
    for (int s = 0; s < 4; ++s) w1f[s] = wf[(16 + s) * 64 + lane];
  } else {
    const float s0 = (g < 2) ? 1.0f : 0.125f;
#pragma unroll
    for (int n = 0; n < 8; ++n) {
      const int o = 16 * n + c15;
      const float* p = W0 + o * 48 + 8 * g;
      const floatx4 v0 = *reinterpret_cast<const floatx4*>(p);
      const floatx4 v1 = *reinterpret_cast<const floatx4*>(p + 4);
      short8 f;
      f[0] = bfr(v0.x * s0); f[1] = bfr(v0.y * s0);
      f[2] = bfr(v0.z * s0); f[3] = bfr(v0.w * s0);
      f[4] = bfr(v1.x * s0); f[5] = bfr(v1.y * s0);
      f[6] = bfr(v1.z * s0); f[7] = bfr(v1.w * s0);
      w0f[n][0] = f;
      short8 f1;
      if (g < 2) {
        const float* p1 = W0 + o * 48 + 32 + 8 * g;
        const floatx4 u0 = *reinterpret_cast<const floatx4*>(p1);
        const floatx4 u1 = *reinterpret_cast<const floatx4*>(p1 + 4);
        f1[0] = bfr(u0.x * 0.125f); f1[1] = bfr(u0.y * 0.125f);
        f1[2] = bfr(u0.z * 0.125f); f1[3] = bfr(u0.w * 0.125f);
        f1[4] = bfr(u1.x * 0.125f); f1[5] = bfr(u1.y * 0.125f);
        f1[6] = bfr(u1.z * 0.125f); f1[7] = bfr(u1.w * 0.125f);
      } else {
#pragma unroll
        for (int j = 0; j < 8; ++j) f1[j] = 0;
        if (g == 2) f1[0] = bfr(b0[o]);
      }
      w0f[n][1] = f1;
    }
#pragma unroll
    for (int s = 0; s < 4; ++s) {
      const float* p = W1 + c15 * 128;
      short8 f;
#pragma unroll
      for (int j = 0; j < 8; ++j)
        f[j] = bfr(p[32 * s + 16 * (j >> 2) + 4 * g + (j & 3)]);
      w1f[s] = f;
    }
  }

  const int cc = 2 * (g & 1);   // chunk pair base for this lane's 8 channels
  const bool lo = (g < 2);
  const int col = 1 + c15;

  // ---- stage x 18x18 window (rows h0-2.., cols w0-2..), zero-padded ----
  for (int f = lane; f < 18 * 18 * 4; f += 64) {
    const int row = f / 72;
    const int rem = f - row * 72;
    const int cl = rem >> 2;
    const int q = rem & 3;
    const int gh = h0 - 2 + row;
    const int gw = w0 - 2 + cl;
    floatx4 v = {0.f, 0.f, 0.f, 0.f};
    if ((unsigned)gh < (unsigned)NH && (unsigned)gw < (unsigned)NW)
      v = *reinterpret_cast<const floatx4*>(
          xin + (((size_t)b * NH + gh) * NW + gw) * NC + 4 * q);
    *addr(xst, row, cl, q) = v;
  }
  __syncthreads();

  uint64_t mball;

  // rolling-partial + center for row ROW of buffer BUF
#define PART(BUF, DST, CEN, ROW)                                             \
  {                                                                          \
    const floatx4 L0 = *addr(BUF, (ROW), col - 1, cc);                       \
    const floatx4 L1 = *addr(BUF, (ROW), col - 1, cc + 1);                   \
    const floatx4 C0 = *addr(BUF, (ROW), col, cc);                           \
    const floatx4 C1 = *addr(BUF, (ROW), col, cc + 1);                       \
    const floatx4 R0 = *addr(BUF, (ROW), col + 1, cc);                       \
    const floatx4 R1 = *addr(BUF, (ROW), col + 1, cc + 1);                   \
    DST[0] = lo ? (R0.x - L0.x) : (L0.x + 2.f * C0.x + R0.x);                \
    DST[1] = lo ? (R0.y - L0.y) : (L0.y + 2.f * C0.y + R0.y);                \
    DST[2] = lo ? (R0.z - L0.z) : (L0.z + 2.f * C0.z + R0.z);                \
    DST[3] = lo ? (R0.w - L0.w) : (L0.w + 2.f * C0.w + R0.w);                \
    DST[4] = lo ? (R1.x - L1.x) : (L1.x + 2.f * C1.x + R1.x);                \
    DST[5] = lo ? (R1.y - L1.y) : (L1.y + 2.f * C1.y + R1.y);                \
    DST[6] = lo ? (R1.z - L1.z) : (L1.z + 2.f * C1.z + R1.z);                \
    DST[7] = lo ? (R1.w - L1.w) : (L1.w + 2.f * C1.w + R1.w);                \
    CEN[0] = C0.x; CEN[1] = C0.y; CEN[2] = C0.z; CEN[3] = C0.w;              \
    CEN[4] = C1.x; CEN[5] = C1.y; CEN[6] = C1.z; CEN[7] = C1.w;              \
  }

  // shared MLP core: HP/HC/HN/CN -> acc2 (dx for this lane's 4 channels)
#define MLP(HP, HC, HN, CN, ACC2)                                            \
  {                                                                          \
    short8 a0, a1;                                                           \
    _Pragma("unroll")                                                        \
    for (int j = 0; j < 8; ++j) {                                            \
      const float comb =                                                     \
          lo ? (HP[j] + 2.f * HC[j] + HN[j]) : (HN[j] - HP[j]);              \
      const short sb = bfr(comb);                                            \
      a0[j] = lo ? bfr(CN[j]) : sb;                                          \
      a1[j] = lo ? sb : (short)0;                                            \
    }                                                                        \
    if (g == 2) a1[0] = bfr(1.0f);                                           \
    floatx4 acc[8];                                                          \
    _Pragma("unroll")                                                        \
    for (int n = 0; n < 8; ++n) acc[n] = floatx4{0.f, 0.f, 0.f, 0.f};        \
    _Pragma("unroll")                                                        \
    for (int n = 0; n < 8; ++n)                                              \
      acc[n] = __builtin_amdgcn_mfma_f32_16x16x32_bf16(w0f[n][0], a0,        \
                                                       acc[n], 0, 0, 0);     \
    _Pragma("unroll")                                                        \
    for (int n = 0; n < 8; ++n)                                              \
      acc[n] = __builtin_amdgcn_mfma_f32_16x16x32_bf16(w0f[n][1], a1,        \
                                                       acc[n], 0, 0, 0);     \
    ACC2 = floatx4{0.f, 0.f, 0.f, 0.f};                                      \
    _Pragma("unroll")                                                        \
    for (int s = 0; s < 4; ++s) {                                            \
      short8 b2;                                                             \
      _Pragma("unroll")                                                      \
      for (int j = 0; j < 8; ++j)                                            \
        b2[j] = bfr(fmaxf(acc[2 * s + (j >> 2)][j & 3], 0.f));               \
      ACC2 = __builtin_amdgcn_mfma_f32_16x16x32_bf16(w1f[s], b2,             \
                                                     ACC2, 0, 0, 0);         \
    }                                                                        \
  }

  // step-1 row: mid row MR (= r4+K), stage center row MR+1; write mid in LDS
#define MT1(K, HP, HC, HN, CN)                                               \
  {                                                                          \
    const int mr = r4 + (K);                                                 \
    floatx4 acc2;                                                            \
    MLP(HP, HC, HN, CN, acc2)                                                \
    const floatx4 xv = *addr(xst, mr + 1, col, g);                           \
    const float mk = (float)((mball >> (16 * (K) + c15)) & 1ull);            \
    const float mk03 = (g == 0) ? 0.f : mk;                                  \
    const bool valid = ((unsigned)(h0 - 1 + mr) < (unsigned)NH) &&           \
                       ((unsigned)(w0 - 1 + c15) < (unsigned)NW);            \
    const float vm = valid ? 1.f : 0.f;                                      \
    floatx4 ov;                                                              \
    ov.x = (xv.x + acc2.x * mk03) * vm;                                      \
    ov.y = (xv.y + acc2.y * mk03) * vm;                                      \
    ov.z = (xv.z + acc2.z * mk03) * vm;                                      \
    ov.w = (xv.w + acc2.w * mk) * vm;                                        \
    *addr(mid, mr, c15, g) = ov;                                             \
  }

  // step-2 row: out row OR (= r4+K), mid center row OR+1; predicated store
#define MT2(K, HP, HC, HN, CN)                                               \
  {                                                                          \
    const int orr = r4 + (K);                                                \
    floatx4 acc2;                                                            \
    MLP(HP, HC, HN, CN, acc2)                                                \
    const floatx4 xv = *addr(mid, orr + 1, col, g);                          \
    const float mk = (float)((mball >> (16 * (K) + c15)) & 1ull);            \
    const float mk03 = (g == 0) ? 0.f : mk;                                  \
    floatx4 ov;                                                              \
    ov.x = xv.x + acc2.x * mk03;                                             \
    ov.y = xv.y + acc2.y * mk03;                                             \
    ov.z = xv.z + acc2.z * mk03;                                             \
    ov.w = xv.w + acc2.w * mk;                                               \
    if (c15 < TO && ((unsigned)(h0 + orr) < (unsigned)NH) &&                 \
        ((unsigned)(w0 + c15) < (unsigned)NW)) {                             \
      const size_t cellg = ((size_t)(b * NH + h0 + orr)) * NW + w0 + c15;    \
      *reinterpret_cast<floatx4*>(xout + cellg * NC + 4 * g) = ov;           \
    }                                                                        \
  }

  // ---- step 1: 16 mid rows (gh = h0-1+mr), 4 groups of 4 ----
#pragma unroll 1
  for (int T = 0; T < 4; ++T) {
    const int r4 = 4 * T;
    {
      const int cellg =
          (b * NH + h0 - 1 + r4 + (lane >> 4)) * NW + w0 - 1 + c15;
      uint32_t r0, r1;
      tf2x32(fa0, fa1, 0u, (uint32_t)cellg, r0, r1);
      const uint32_t bits = r0 ^ r1;
      const float u = __uint_as_float((bits >> 9) | 0x3F800000u) - 1.0f;
      mball = __ballot(u > 0.5f);
    }
    float hpA[8], hpB[8], hpC[8], cnA[8], cnB[8], cnC[8];
    PART(xst, hpA, cnA, r4 + 0)
    PART(xst, hpB, cnB, r4 + 1)
    PART(xst, hpC, cnC, r4 + 2)
    MT1(0, hpA, hpB, hpC, cnB)
    PART(xst, hpA, cnA, r4 + 3)
    MT1(1, hpB, hpC, hpA, cnC)
    PART(xst, hpB, cnB, r4 + 4)
    MT1(2, hpC, hpA, hpB, cnA)
    PART(xst, hpC, cnC, r4 + 5)
    MT1(3, hpA, hpB, hpC, cnB)
  }
  __syncthreads();   // mid complete before step-2 reads

  // ---- step 2: 14 out rows (gh = h0+or), 3 full groups + 2-row tail ----
#pragma unroll 1
  for (int T = 0; T < 3; ++T) {
    const int r4 = 4 * T;
    {
      const int cellg = (b * NH + h0 + r4 + (lane >> 4)) * NW + w0 + c15;
      uint32_t r0, r1;
      tf2x32(fb0, fb1, 0u, (uint32_t)cellg, r0, r1);
      const uint32_t bits = r0 ^ r1;
      const float u = __uint_as_float((bits >> 9) | 0x3F800000u) - 1.0f;
      mball = __ballot(u > 0.5f);
    }
    float hpA[8], hpB[8], hpC[8], cnA[8], cnB[8], cnC[8];
    PART(mid, hpA, cnA, r4 + 0)
    PART(mid, hpB, cnB, r4 + 1)
    PART(mid, hpC, cnC, r4 + 2)
    MT2(0, hpA, hpB, hpC, cnB)
    PART(mid, hpA, cnA, r4 + 3)
    MT2(1, hpB, hpC, hpA, cnC)
    PART(mid, hpB, cnB, r4 + 4)
    MT2(2, hpC, hpA, hpB, cnA)
    PART(mid, hpC, cnC, r4 + 5)
    MT2(3, hpA, hpB, hpC, cnB)
  }
  {
    const int r4 = 12;   // tail: out rows 12,13
    {
      const int cellg = (b * NH + h0 + r4 + (lane >> 4)) * NW + w0 + c15;
      uint32_t r0, r1;
      tf2x32(fb0, fb1, 0u, (uint32_t)cellg, r0, r1);
      const uint32_t bits = r0 ^ r1;
      const float u = __uint_as_float((bits >> 9) | 0x3F800000u) - 1.0f;
      mball = __ballot(u > 0.5f);
    }
    float hpA[8], hpB[8], hpC[8], cnA[8], cnB[8], cnC[8];
    PART(mid, hpA, cnA, 12)
    PART(mid, hpB, cnB, 13)
    PART(mid, hpC, cnC, 14)
    MT2(0, hpA, hpB, hpC, cnB)
    PART(mid, hpA, cnA, 15)
    MT2(1, hpB, hpC, hpA, cnC)
  }
#undef PART
#undef MLP
#undef MT1
#undef MT2
}

extern "C" void kernel_launch(void* const* d_in, const int* in_sizes, int n_in,
                              void* d_out, int out_size, void* d_ws, size_t ws_size,
                              hipStream_t stream) {
  const float* x  = (const float*)d_in[0];
  const float* W0 = (const float*)d_in[1];
  const float* b0 = (const float*)d_in[2];
  const float* W1 = (const float*)d_in[3];
  float* out = (float*)d_out;

  const bool pre = ws_size >= (size_t)20 * 64 * 16;   // 20 fragments
  short* wbuf = (short*)d_ws;

  uint32_t fa0, fa1, fb0, fb1;
  tf2x32(0u, 42u, 0u, 0u, fa0, fa1);  // fold_in(key(42), 0)
  tf2x32(0u, 42u, 0u, 1u, fb0, fb1);  // fold_in(key(42), 1)

  dim3 grid(NB * NT * NT), block(64);
  if (pre) {
    ca_prep<<<20, 64, 0, stream>>>(W0, b0, W1, wbuf);
    ca_fused<true><<<grid, block, 0, stream>>>(x, out, W0, b0, W1, wbuf,
                                               fa0, fa1, fb0, fb1);
  } else {
    ca_fused<false><<<grid, block, 0, stream>>>(x, out, W0, b0, W1, nullptr,
                                                fa0, fa1, fb0, fb1);
  }
}

// Round 22
// 57.732 us; speedup vs baseline: 1.5698x; 1.5698x over previous
//
#include <hip/hip_runtime.h>
#include <hip/hip_bf16.h>
#include <stdint.h>

// CA model: B=8, H=256, W=256, C=16, HID=128, steps=2 (fixed by setup_inputs).
// Round 22: REVERT to round 19 (best measured, 57.8us). Round 21's temporal
// fusion regressed (90.6us): doubled serial chain per block, 39KB LDS ->
// 4 blocks/CU, 1.22x redundant row work, and tmp was L3-resident anyway so
// the eliminated round-trip was nearly free. Structure: 4 vertical tiles per
// wave, dbuf xs, async-STAGE split, separable-sobel rolling partials with
// center-saving, tau-permuted GEMM2, K-pad bias, 20-block parallel prep.

#define NB 8
#define NH 256
#define NW 256
#define NC 16
#define WOFF 65536   // tmp offset in d_ws when prep region in use (20KB used)

typedef __attribute__((ext_vector_type(8))) short short8;
typedef __attribute__((ext_vector_type(4))) float floatx4;

__host__ __device__ inline void tf2x32(uint32_t k0, uint32_t k1,
                                       uint32_t x0, uint32_t x1,
                                       uint32_t& o0, uint32_t& o1) {
  const uint32_t ks2 = k0 ^ k1 ^ 0x1BD11BDAu;
  x0 += k0; x1 += k1;
#define RL(v, d) (((v) << (d)) | ((v) >> (32 - (d))))
#define R4(a, b, c, d)                          \
  x0 += x1; x1 = RL(x1, a); x1 ^= x0;           \
  x0 += x1; x1 = RL(x1, b); x1 ^= x0;           \
  x0 += x1; x1 = RL(x1, c); x1 ^= x0;           \
  x0 += x1; x1 = RL(x1, d); x1 ^= x0;
  R4(13, 15, 26, 6);  x0 += k1;  x1 += ks2 + 1u;
  R4(17, 29, 16, 24); x0 += ks2; x1 += k0 + 2u;
  R4(13, 15, 26, 6);  x0 += k0;  x1 += k1 + 3u;
  R4(17, 29, 16, 24); x0 += k1;  x1 += ks2 + 4u;
  R4(13, 15, 26, 6);  x0 += ks2; x1 += k0 + 5u;
#undef R4
#undef RL
  o0 = x0; o1 = x1;
}

__device__ inline short bfr(float x) {
  __hip_bfloat16 h = __float2bfloat16(x);
  return *reinterpret_cast<short*>(&h);
}

// ---- parallel prep: 20 blocks x 64 lanes, one fragment per block ----
// W0 sobel columns pre-scaled by 1/8 (power-of-2, bit-identical products) so
// kernel tap weights are inline consts; K-pad bias at k=48 (A=b0[o], B=1).
__global__ __launch_bounds__(64) void ca_prep(
    const float* __restrict__ W0, const float* __restrict__ b0,
    const float* __restrict__ W1, short* __restrict__ wbuf) {
  const int lane = threadIdx.x;
  const int c15 = lane & 15;
  const int g = lane >> 4;
  const int fi = blockIdx.x;   // 0..19
  short8 f;
  if (fi < 16) {
    const int n = fi >> 1;
    const int o = 16 * n + c15;
    if ((fi & 1) == 0) {
      const float s0 = (g < 2) ? 1.0f : 0.125f;   // identity | c1(scaled)
      const float* p = W0 + o * 48 + 8 * g;
      const floatx4 v0 = *reinterpret_cast<const floatx4*>(p);
      const floatx4 v1 = *reinterpret_cast<const floatx4*>(p + 4);
      f[0] = bfr(v0.x * s0); f[1] = bfr(v0.y * s0);
      f[2] = bfr(v0.z * s0); f[3] = bfr(v0.w * s0);
      f[4] = bfr(v1.x * s0); f[5] = bfr(v1.y * s0);
      f[6] = bfr(v1.z * s0); f[7] = bfr(v1.w * s0);
    } else {
      if (g < 2) {   // c2 columns (scaled)
        const float* p1 = W0 + o * 48 + 32 + 8 * g;
        const floatx4 u0 = *reinterpret_cast<const floatx4*>(p1);
        const floatx4 u1 = *reinterpret_cast<const floatx4*>(p1 + 4);
        f[0] = bfr(u0.x * 0.125f); f[1] = bfr(u0.y * 0.125f);
        f[2] = bfr(u0.z * 0.125f); f[3] = bfr(u0.w * 0.125f);
        f[4] = bfr(u1.x * 0.125f); f[5] = bfr(u1.y * 0.125f);
        f[6] = bfr(u1.z * 0.125f); f[7] = bfr(u1.w * 0.125f);
      } else {
#pragma unroll
        for (int j = 0; j < 8; ++j) f[j] = 0;
        if (g == 2) f[0] = bfr(b0[o]);   // A[o][48] = b0[o] (K-pad bias)
      }
    }
  } else {
    const int s = fi - 16;   // tau(s,8g+j)=32s+16*(j>>2)+4g+(j&3)
    const float* p = W1 + c15 * 128;
#pragma unroll
    for (int j = 0; j < 8; ++j)
      f[j] = bfr(p[32 * s + 16 * (j >> 2) + 4 * g + (j & 3)]);
  }
  reinterpret_cast<short8*>(wbuf)[fi * 64 + lane] = f;
}

template <bool PRE>
__global__ __launch_bounds__(64, 2) void ca_step(
    const float* __restrict__ xin, float* __restrict__ xout,
    const float* __restrict__ W0, const float* __restrict__ b0,
    const float* __restrict__ W1, const short* __restrict__ wfrag,
    uint32_t fk0, uint32_t fk1) {
  // two fp32 x tiles + halo (6 rows x 18 cols), 16B-chunk XOR-swizzled
  __shared__ float xs[2][6 * 18 * 16];

  const int tid = threadIdx.x;
  const int bt = blockIdx.x;
  const int wt = bt & 15;
  const int ht16 = (bt >> 4) & 15;
  const int b = bt >> 8;
  const int h0 = ht16 * 16;
  const int w0 = wt * 16;

  const int lane = tid;
  const int c15 = lane & 15;
  const int g = lane >> 4;

  auto xsaddr = [&](float* base, int row, int col, int chunk) -> floatx4* {
    const int off = (row * 18 + col) * 64 + ((chunk ^ ((col >> 1) & 3)) << 4);
    return reinterpret_cast<floatx4*>(reinterpret_cast<char*>(base) + off);
  };

  // ---- weight fragments, loaded once per wave ----
  short8 w0f[8][2];
  short8 w1f[4];
  if constexpr (PRE) {
    const short8* wf = reinterpret_cast<const short8*>(wfrag);
#pragma unroll
    for (int n = 0; n < 8; ++n) {
      w0f[n][0] = wf[(2 * n) * 64 + lane];
      w0f[n][1] = wf[(2 * n + 1) * 64 + lane];
    }
#pragma unroll
    for (int s = 0; s < 4; ++s) w1f[s] = wf[(16 + s) * 64 + lane];
  } else {
    const float s0 = (g < 2) ? 1.0f : 0.125f;
#pragma unroll
    for (int n = 0; n < 8; ++n) {
      const int o = 16 * n + c15;
      const float* p = W0 + o * 48 + 8 * g;
      const floatx4 v0 = *reinterpret_cast<const floatx4*>(p);
      const floatx4 v1 = *reinterpret_cast<const floatx4*>(p + 4);
      short8 f;
      f[0] = bfr(v0.x * s0); f[1] = bfr(v0.y * s0);
      f[2] = bfr(v0.z * s0); f[3] = bfr(v0.w * s0);
      f[4] = bfr(v1.x * s0); f[5] = bfr(v1.y * s0);
      f[6] = bfr(v1.z * s0); f[7] = bfr(v1.w * s0);
      w0f[n][0] = f;
      short8 f1;
      if (g < 2) {
        const float* p1 = W0 + o * 48 + 32 + 8 * g;
        const floatx4 u0 = *reinterpret_cast<const floatx4*>(p1);
        const floatx4 u1 = *reinterpret_cast<const floatx4*>(p1 + 4);
        f1[0] = bfr(u0.x * 0.125f); f1[1] = bfr(u0.y * 0.125f);
        f1[2] = bfr(u0.z * 0.125f); f1[3] = bfr(u0.w * 0.125f);
        f1[4] = bfr(u1.x * 0.125f); f1[5] = bfr(u1.y * 0.125f);
        f1[6] = bfr(u1.z * 0.125f); f1[7] = bfr(u1.w * 0.125f);
      } else {
#pragma unroll
        for (int j = 0; j < 8; ++j) f1[j] = 0;
        if (g == 2) f1[0] = bfr(b0[o]);
      }
      w0f[n][1] = f1;
    }
#pragma unroll
    for (int s = 0; s < 4; ++s) {
      const float* p = W1 + c15 * 128;
      short8 f;
#pragma unroll
      for (int j = 0; j < 8; ++j)
        f[j] = bfr(p[32 * s + 16 * (j >> 2) + 4 * g + (j & 3)]);
      w1f[s] = f;
    }
  }

  const int cc = 2 * (g & 1);   // chunk pair base for this lane's 8 channels
  const bool lo = (g < 2);
  const int col = 1 + c15;

  // ---- staging helpers: 432 16B chunks per tile, 7 per lane ----
  auto load_ph = [&](int h0t, floatx4* stg) {
#pragma unroll
    for (int i = 0; i < 7; ++i) {
      const int f = lane + 64 * i;
      floatx4 v = {0.f, 0.f, 0.f, 0.f};
      if (f < 432) {
        const int row = f / 72;
        const int rem = f - row * 72;
        const int cl = rem >> 2;
        const int q = rem & 3;
        const int gh = h0t - 1 + row;
        const int gw = w0 - 1 + cl;
        if ((unsigned)gh < (unsigned)NH && (unsigned)gw < (unsigned)NW)
          v = *reinterpret_cast<const floatx4*>(
              xin + (((size_t)b * NH + gh) * NW + gw) * NC + 4 * q);
      }
      stg[i] = v;
    }
  };
  auto write_ph = [&](float* buf, const floatx4* stg) {
#pragma unroll
    for (int i = 0; i < 7; ++i) {
      const int f = lane + 64 * i;
      if (f < 432) {
        const int row = f / 72;
        const int rem = f - row * 72;
        const int cl = rem >> 2;
        const int q = rem & 3;
        *xsaddr(buf, row, cl, q) = stg[i];
      }
    }
  };

  // rolling-partial: lane's partial + center for row ROW
  //   lo (c2 feeder): Hd = v[col+1] - v[col-1]
  //   hi (c1 feeder): Hs = v[col-1] + 2*v[col] + v[col+1]
#define PART(DST, CEN, ROW)                                                  \
  {                                                                          \
    const floatx4 L0 = *xsaddr(xsb, (ROW), col - 1, cc);                     \
    const floatx4 L1 = *xsaddr(xsb, (ROW), col - 1, cc + 1);                 \
    const floatx4 C0 = *xsaddr(xsb, (ROW), col, cc);                         \
    const floatx4 C1 = *xsaddr(xsb, (ROW), col, cc + 1);                     \
    const floatx4 R0 = *xsaddr(xsb, (ROW), col + 1, cc);                     \
    const floatx4 R1 = *xsaddr(xsb, (ROW), col + 1, cc + 1);                 \
    DST[0] = lo ? (R0.x - L0.x) : (L0.x + 2.f * C0.x + R0.x);                \
    DST[1] = lo ? (R0.y - L0.y) : (L0.y + 2.f * C0.y + R0.y);                \
    DST[2] = lo ? (R0.z - L0.z) : (L0.z + 2.f * C0.z + R0.z);                \
    DST[3] = lo ? (R0.w - L0.w) : (L0.w + 2.f * C0.w + R0.w);                \
    DST[4] = lo ? (R1.x - L1.x) : (L1.x + 2.f * C1.x + R1.x);                \
    DST[5] = lo ? (R1.y - L1.y) : (L1.y + 2.f * C1.y + R1.y);                \
    DST[6] = lo ? (R1.z - L1.z) : (L1.z + 2.f * C1.z + R1.z);                \
    DST[7] = lo ? (R1.w - L1.w) : (L1.w + 2.f * C1.w + R1.w);                \
    CEN[0] = C0.x; CEN[1] = C0.y; CEN[2] = C0.z; CEN[3] = C0.w;              \
    CEN[4] = C1.x; CEN[5] = C1.y; CEN[6] = C1.z; CEN[7] = C1.w;              \
  }

  // one output row: combine partials, build fragments, MFMA, epilogue
#define MTSTEP(MTI, HP, HC, HN, CN)                                          \
  {                                                                          \
    const int r = 1 + (MTI);                                                 \
    short8 a0, a1;                                                           \
    _Pragma("unroll")                                                        \
    for (int j = 0; j < 8; ++j) {                                            \
      const float comb =                                                     \
          lo ? (HP[j] + 2.f * HC[j] + HN[j]) : (HN[j] - HP[j]);              \
      const short sb = bfr(comb);                                            \
      a0[j] = lo ? bfr(CN[j]) : sb;                                          \
      a1[j] = lo ? sb : (short)0;                                            \
    }                                                                        \
    if (g == 2) a1[0] = bfr(1.0f);                                           \
    floatx4 acc[8];                                                          \
    _Pragma("unroll")                                                        \
    for (int n = 0; n < 8; ++n) acc[n] = floatx4{0.f, 0.f, 0.f, 0.f};        \
    _Pragma("unroll")                                                        \
    for (int n = 0; n < 8; ++n)                                              \
      acc[n] = __builtin_amdgcn_mfma_f32_16x16x32_bf16(w0f[n][0], a0,        \
                                                       acc[n], 0, 0, 0);     \
    _Pragma("unroll")                                                        \
    for (int n = 0; n < 8; ++n)                                              \
      acc[n] = __builtin_amdgcn_mfma_f32_16x16x32_bf16(w0f[n][1], a1,        \
                                                       acc[n], 0, 0, 0);     \
    floatx4 acc2 = {0.f, 0.f, 0.f, 0.f};                                     \
    _Pragma("unroll")                                                        \
    for (int s = 0; s < 4; ++s) {                                            \
      short8 b2;                                                             \
      _Pragma("unroll")                                                      \
      for (int j = 0; j < 8; ++j)                                            \
        b2[j] = bfr(fmaxf(acc[2 * s + (j >> 2)][j & 3], 0.f));               \
      acc2 = __builtin_amdgcn_mfma_f32_16x16x32_bf16(w1f[s], b2,             \
                                                     acc2, 0, 0, 0);         \
    }                                                                        \
    const floatx4 xv = *xsaddr(xsb, r, col, g);                              \
    const float mk = (float)((mball >> (16 * (MTI) + c15)) & 1ull);          \
    const float mk03 = (g == 0) ? 0.f : mk;                                  \
    floatx4 ov;                                                              \
    ov.x = xv.x + acc2.x * mk03;                                             \
    ov.y = xv.y + acc2.y * mk03;                                             \
    ov.z = xv.z + acc2.z * mk03;                                             \
    ov.w = xv.w + acc2.w * mk;                                               \
    const size_t cellg = ((size_t)(b * NH + h0t + (MTI))) * NW + w0 + c15;   \
    *reinterpret_cast<floatx4*>(xout + cellg * NC + 4 * g) = ov;             \
  }

  // tile 0 staged directly
  {
    floatx4 s0[7];
    load_ph(h0, s0);
    write_ph(reinterpret_cast<float*>(xs[0]), s0);
  }
  __syncthreads();

  int cur = 0;
#pragma unroll 1
  for (int t = 0; t < 4; ++t) {
    const int h0t = h0 + 4 * t;

    // async-STAGE: issue next tile's global loads BEFORE compute
    floatx4 stg[7];
    if (t < 3) {
      load_ph(h0t + 4, stg);
      asm volatile("" ::: "memory");   // pin loads above the compute phase
    }

    // fire mask: lane -> (row=lane>>4, col=lane&15), bit = 16*row+col
    uint64_t mball;
    {
      const int cellg = (b * NH + h0t + (lane >> 4)) * NW + w0 + c15;
      uint32_t r0, r1;
      tf2x32(fk0, fk1, 0u, (uint32_t)cellg, r0, r1);
      const uint32_t bits = r0 ^ r1;
      const float u = __uint_as_float((bits >> 9) | 0x3F800000u) - 1.0f;
      mball = __ballot(u > 0.5f);
    }

    float* xsb = reinterpret_cast<float*>(xs[cur]);

    float hpA[8], hpB[8], hpC[8], cnA[8], cnB[8], cnC[8];
    PART(hpA, cnA, 0)
    PART(hpB, cnB, 1)
    PART(hpC, cnC, 2)
    MTSTEP(0, hpA, hpB, hpC, cnB)
    PART(hpA, cnA, 3)
    MTSTEP(1, hpB, hpC, hpA, cnC)
    PART(hpB, cnB, 4)
    MTSTEP(2, hpC, hpA, hpB, cnA)
    PART(hpC, cnC, 5)
    MTSTEP(3, hpA, hpB, hpC, cnB)

    if (t < 3) {
      __syncthreads();   // WAR: reads of xs[cur^1] (tile t-1) fully drained
      write_ph(reinterpret_cast<float*>(xs[cur ^ 1]), stg);
      __syncthreads();   // staging visible before tile t+1 reads
      cur ^= 1;
    }
  }
#undef PART
#undef MTSTEP
}

extern "C" void kernel_launch(void* const* d_in, const int* in_sizes, int n_in,
                              void* d_out, int out_size, void* d_ws, size_t ws_size,
                              hipStream_t stream) {
  const float* x  = (const float*)d_in[0];
  const float* W0 = (const float*)d_in[1];
  const float* b0 = (const float*)d_in[2];
  const float* W1 = (const float*)d_in[3];
  float* out = (float*)d_out;

  const size_t tmp_bytes = (size_t)NB * NH * NW * NC * 4;   // 32 MiB
  const bool pre = ws_size >= (size_t)WOFF + tmp_bytes;
  short* wbuf = (short*)d_ws;
  float* tmp = pre ? (float*)((char*)d_ws + WOFF) : (float*)d_ws;

  uint32_t fa0, fa1, fb0, fb1;
  tf2x32(0u, 42u, 0u, 0u, fa0, fa1);  // fold_in(key(42), 0)
  tf2x32(0u, 42u, 0u, 1u, fb0, fb1);  // fold_in(key(42), 1)

  dim3 grid(NB * (NH / 16) * (NW / 16)), block(64);
  if (pre) {
    ca_prep<<<20, 64, 0, stream>>>(W0, b0, W1, wbuf);
    ca_step<true><<<grid, block, 0, stream>>>(x, tmp, W0, b0, W1, wbuf, fa0, fa1);
    ca_step<true><<<grid, block, 0, stream>>>(tmp, out, W0, b0, W1, wbuf, fb0, fb1);
  } else {
    ca_step<false><<<grid, block, 0, stream>>>(x, tmp, W0, b0, W1, nullptr, fa0, fa1);
    ca_step<false><<<grid, block, 0, stream>>>(tmp, out, W0, b0, W1, nullptr, fb0, fb1);
  }
}